// Round 1
// baseline (702.324 us; speedup 1.0000x reference)
//
#include <hip/hip_runtime.h>
#include <utility>
#include <cstddef>

// ---------------- compile-time Ivanic-Ruedenberg tables ----------------

struct Term { int o; int r; int a; float c; };
struct LTable { int n; Term t[1024]; };

constexpr double csqrt(double x) {
    if (x <= 0.0) return 0.0;
    double g = x < 1.0 ? 1.0 : x;
    for (int i = 0; i < 50; ++i) g = 0.5 * (g + x / g);
    return g;
}
constexpr int cabs_i(int x) { return x < 0 ? -x : x; }
constexpr int cmax_i(int a, int b) { return a > b ? a : b; }

// add scaled P(i,l,a,b) terms (sparse products R1[rij]*Dprev[ab])
constexpr void add_p(LTable& T, int o, double scale, int i, int a, int b, int l) {
    int lp = l - 1;
    int np = 2 * lp + 1;
    int row = i + 1;
    if (b == l) {
        T.t[T.n++] = Term{o, row * 3 + 2, (a + lp) * np + 2 * lp, (float)scale};
        T.t[T.n++] = Term{o, row * 3 + 0, (a + lp) * np + 0,      (float)(-scale)};
    } else if (b == -l) {
        T.t[T.n++] = Term{o, row * 3 + 2, (a + lp) * np + 0,      (float)scale};
        T.t[T.n++] = Term{o, row * 3 + 0, (a + lp) * np + 2 * lp, (float)scale};
    } else {
        T.t[T.n++] = Term{o, row * 3 + 1, (a + lp) * np + (b + lp), (float)scale};
    }
}

constexpr LTable ru_table(int l) {
    LTable T{};
    int n = 2 * l + 1;
    for (int m = -l; m <= l; ++m) {
        for (int mp = -l; mp <= l; ++mp) {
            double denom = (cabs_i(mp) == l) ? (double)((2 * l) * (2 * l - 1))
                                             : (double)((l + mp) * (l - mp));
            double d0 = (m == 0) ? 1.0 : 0.0;
            double u = csqrt((double)((l + m) * (l - m)) / denom);
            double v = 0.5 * csqrt((1.0 + d0) * (l + cabs_i(m) - 1) * (l + cabs_i(m)) / denom)
                       * (1.0 - 2.0 * d0);
            double w = -0.5 * csqrt((double)cmax_i(l - cabs_i(m) - 1, 0) * (l - cabs_i(m)) / denom)
                       * (1.0 - d0);
            int o = (m + l) * n + (mp + l);
            if (u != 0.0) add_p(T, o, u, 0, m, mp, l);
            if (v != 0.0) {
                if (m == 0) {
                    add_p(T, o, v, 1, 1, mp, l);
                    add_p(T, o, v, -1, -1, mp, l);
                } else if (m > 0) {
                    double s = (m == 1) ? csqrt(2.0) : 1.0;
                    add_p(T, o, v * s, 1, m - 1, mp, l);
                    if (m != 1) add_p(T, o, -v, -1, -m + 1, mp, l);
                } else {
                    if (m != -1) add_p(T, o, v, 1, m + 1, mp, l);
                    double s = (m == -1) ? csqrt(2.0) : 1.0;
                    add_p(T, o, v * s, -1, -m - 1, mp, l);
                }
            }
            if (w != 0.0) {
                if (m > 0) {
                    add_p(T, o, w, 1, m + 1, mp, l);
                    add_p(T, o, w, -1, -m - 1, mp, l);
                } else {
                    add_p(T, o, w, 1, m - 1, mp, l);
                    add_p(T, o, -w, -1, -m + 1, mp, l);
                }
            }
        }
    }
    return T;
}

inline constexpr LTable T2 = ru_table(2);
inline constexpr LTable T3 = ru_table(3);
inline constexpr LTable T4 = ru_table(4);

// apply table fully unrolled: all indices are literals -> arrays stay in VGPRs
template<const LTable& T, size_t... I>
__device__ __forceinline__ void apply_terms(float* __restrict__ D,
                                            const float* __restrict__ R1,
                                            const float* __restrict__ P,
                                            std::index_sequence<I...>) {
    ((D[T.t[I].o] += T.t[I].c * R1[T.t[I].r] * P[T.t[I].a]), ...);
}

// ---------------- output layout helpers ----------------
// 25x25 block diagonal: blocks at offsets b*b with dim 2b+1, b=0..4

constexpr int blk_of(int x) { return x == 0 ? 0 : x < 4 ? 1 : x < 9 ? 2 : x < 16 ? 3 : 4; }

__device__ __forceinline__ int blk_rt(int x) {
    return (x == 0) ? 0 : (x < 4) ? 1 : (x < 9) ? 2 : (x < 16) ? 3 : 4;
}

template<int E>
__device__ __forceinline__ float pick(const float* D1, const float* D2,
                                      const float* D3, const float* D4) {
    if constexpr (E >= 625) {
        return 0.0f;
    } else {
        constexpr int r = E / 25, c = E % 25;
        constexpr int b = blk_of(r);
        if constexpr (blk_of(c) != b) {
            return 0.0f;
        } else {
            constexpr int off = b * b, d = 2 * b + 1;
            constexpr int li = (r - off) * d + (c - off);
            if constexpr (b == 0) return 1.0f;
            else if constexpr (b == 1) return D1[li];
            else if constexpr (b == 2) return D2[li];
            else if constexpr (b == 3) return D3[li];
            else return D4[li];
        }
    }
}

// stage one entry of this round into LDS (only nonzero-block entries)
template<int E>
__device__ __forceinline__ void stage_one(float* __restrict__ slds, int p,
                                          const float* D1, const float* D2,
                                          const float* D3, const float* D4) {
    if constexpr (E < 625 && blk_of(E / 25) == blk_of(E % 25)) {
        slds[p * 33 + (E & 31)] = pick<E>(D1, D2, D3, D4);
    }
}

template<int BASE, size_t... I>
__device__ __forceinline__ void stage(float* __restrict__ slds, int p,
                                      const float* D1, const float* D2,
                                      const float* D3, const float* D4,
                                      std::index_sequence<I...>) {
    (stage_one<BASE + (int)I>(slds, p, D1, D2, D3, D4), ...);
}

__device__ __forceinline__ void flush_round(int base, const float* __restrict__ slds,
                                            float* __restrict__ out,
                                            int wave_pbase, int lane, int Ntot) {
    const int el = lane & 31;
    const int half = lane >> 5;
    const int e = base + el;
    const bool ok = e < 625;
    const int r = e / 25;
    const int c = e - r * 25;
    const bool isb = ok && (blk_rt(r) == blk_rt(c));
#pragma unroll
    for (int i = 0; i < 32; ++i) {
        const int p = 2 * i + half;
        const int gp = wave_pbase + p;
        float v = isb ? slds[p * 33 + el] : 0.0f;
        if (ok && gp < Ntot) out[(long long)gp * 625 + e] = v;
    }
}

template<int ROUND>
__device__ __forceinline__ void do_round(float* __restrict__ slds, int lane,
                                         const float* D1, const float* D2,
                                         const float* D3, const float* D4,
                                         float* __restrict__ out,
                                         int wave_pbase, int Ntot) {
    stage<ROUND * 32>(slds, lane, D1, D2, D3, D4, std::make_index_sequence<32>{});
    __syncthreads();
    flush_round(ROUND * 32, slds, out, wave_pbase, lane, Ntot);
    __syncthreads();
}

template<size_t... R>
__device__ __forceinline__ void all_rounds(float* __restrict__ slds, int lane,
                                           const float* D1, const float* D2,
                                           const float* D3, const float* D4,
                                           float* __restrict__ out,
                                           int wave_pbase, int Ntot,
                                           std::index_sequence<R...>) {
    (do_round<(int)R>(slds, lane, D1, D2, D3, D4, out, wave_pbase, Ntot), ...);
}

// ---------------- kernel ----------------

__global__ __launch_bounds__(256, 2)
void wigner_align_z_kernel(const float* __restrict__ xyz, float* __restrict__ out, int Ntot) {
    __shared__ float lds[4][64 * 33];  // per-wave 64 points x 32 entries (+1 pad)

    const int lane = threadIdx.x & 63;
    const int wave = threadIdx.x >> 6;
    const int gp = blockIdx.x * 256 + threadIdx.x;
    const int wave_pbase = blockIdx.x * 256 + wave * 64;

    float x = 0.0f, y = 0.0f, z = 1.0f;
    if (gp < Ntot) {
        x = xyz[3 * gp + 0];
        y = xyz[3 * gp + 1];
        z = xyz[3 * gp + 2];
    }

    // angles without trig: ct = vz (clipped), st = sqrt(1-ct^2), cp/sp from x,y
    const float r2 = x * x + y * y + z * z;
    const float rinv = rsqrtf(fmaxf(r2, 1e-24f));
    const float ct = fminf(fmaxf(z * rinv, -1.0f), 1.0f);
    const float st = sqrtf(fmaxf(1.0f - ct * ct, 0.0f));
    const float rxy2 = x * x + y * y;
    float cp = 1.0f, sp = 0.0f;
    if (rxy2 > 0.0f) {
        const float ri = rsqrtf(rxy2);
        cp = x * ri;
        sp = y * ri;
    }

    // R1 in real-SH l=1 basis order (y,z,x), row-major 3x3
    float D1[9] = {cp,      0.0f, -sp,
                   st * sp, ct,   st * cp,
                   ct * sp, -st,  ct * cp};

    float D2[25] = {};
    apply_terms<T2>(D2, D1, D1, std::make_index_sequence<(size_t)T2.n>{});
    float D3[49] = {};
    apply_terms<T3>(D3, D1, D2, std::make_index_sequence<(size_t)T3.n>{});
    float D4[81] = {};
    apply_terms<T4>(D4, D1, D3, std::make_index_sequence<(size_t)T4.n>{});

    all_rounds(&lds[wave][0], lane, D1, D2, D3, D4, out, wave_pbase, Ntot,
               std::make_index_sequence<20>{});
}

extern "C" void kernel_launch(void* const* d_in, const int* in_sizes, int n_in,
                              void* d_out, int out_size, void* d_ws, size_t ws_size,
                              hipStream_t stream) {
    const float* xyz = (const float*)d_in[0];
    float* out = (float*)d_out;
    const int N = in_sizes[0] / 3;
    const int blocks = (N + 255) / 256;
    hipLaunchKernelGGL(wigner_align_z_kernel, dim3(blocks), dim3(256), 0, stream,
                       xyz, out, N);
}

// Round 3
// 590.016 us; speedup vs baseline: 1.1903x; 1.1903x over previous
//
#include <hip/hip_runtime.h>
#include <utility>
#include <cstddef>

// ---------------- compile-time Ivanic-Ruedenberg tables ----------------

struct Term { int o; int r; int a; float c; };
struct LTable { int n; Term t[1024]; };

constexpr double csqrt(double x) {
    if (x <= 0.0) return 0.0;
    double g = x < 1.0 ? 1.0 : x;
    for (int i = 0; i < 50; ++i) g = 0.5 * (g + x / g);
    return g;
}
constexpr int cabs_i(int x) { return x < 0 ? -x : x; }
constexpr int cmax_i(int a, int b) { return a > b ? a : b; }

constexpr void add_p(LTable& T, int o, double scale, int i, int a, int b, int l) {
    int lp = l - 1;
    int np = 2 * lp + 1;
    int row = i + 1;
    if (b == l) {
        T.t[T.n++] = Term{o, row * 3 + 2, (a + lp) * np + 2 * lp, (float)scale};
        T.t[T.n++] = Term{o, row * 3 + 0, (a + lp) * np + 0,      (float)(-scale)};
    } else if (b == -l) {
        T.t[T.n++] = Term{o, row * 3 + 2, (a + lp) * np + 0,      (float)scale};
        T.t[T.n++] = Term{o, row * 3 + 0, (a + lp) * np + 2 * lp, (float)scale};
    } else {
        T.t[T.n++] = Term{o, row * 3 + 1, (a + lp) * np + (b + lp), (float)scale};
    }
}

constexpr LTable ru_table(int l) {
    LTable T{};
    int n = 2 * l + 1;
    for (int m = -l; m <= l; ++m) {
        for (int mp = -l; mp <= l; ++mp) {
            double denom = (cabs_i(mp) == l) ? (double)((2 * l) * (2 * l - 1))
                                             : (double)((l + mp) * (l - mp));
            double d0 = (m == 0) ? 1.0 : 0.0;
            double u = csqrt((double)((l + m) * (l - m)) / denom);
            double v = 0.5 * csqrt((1.0 + d0) * (l + cabs_i(m) - 1) * (l + cabs_i(m)) / denom)
                       * (1.0 - 2.0 * d0);
            double w = -0.5 * csqrt((double)cmax_i(l - cabs_i(m) - 1, 0) * (l - cabs_i(m)) / denom)
                       * (1.0 - d0);
            int o = (m + l) * n + (mp + l);
            if (u != 0.0) add_p(T, o, u, 0, m, mp, l);
            if (v != 0.0) {
                if (m == 0) {
                    add_p(T, o, v, 1, 1, mp, l);
                    add_p(T, o, v, -1, -1, mp, l);
                } else if (m > 0) {
                    double s = (m == 1) ? csqrt(2.0) : 1.0;
                    add_p(T, o, v * s, 1, m - 1, mp, l);
                    if (m != 1) add_p(T, o, -v, -1, -m + 1, mp, l);
                } else {
                    if (m != -1) add_p(T, o, v, 1, m + 1, mp, l);
                    double s = (m == -1) ? csqrt(2.0) : 1.0;
                    add_p(T, o, v * s, -1, -m - 1, mp, l);
                }
            }
            if (w != 0.0) {
                if (m > 0) {
                    add_p(T, o, w, 1, m + 1, mp, l);
                    add_p(T, o, w, -1, -m - 1, mp, l);
                } else {
                    add_p(T, o, w, 1, m - 1, mp, l);
                    add_p(T, o, -w, -1, -m + 1, mp, l);
                }
            }
        }
    }
    return T;
}

inline constexpr LTable T2 = ru_table(2);
inline constexpr LTable T3 = ru_table(3);
inline constexpr LTable T4 = ru_table(4);

template<const LTable& T, size_t... I>
__device__ __forceinline__ void apply_terms(float* __restrict__ D,
                                            const float* __restrict__ R1,
                                            const float* __restrict__ P,
                                            std::index_sequence<I...>) {
    ((D[T.t[I].o] += T.t[I].c * R1[T.t[I].r] * P[T.t[I].a]), ...);
}

// ---------------- output layout ----------------
// 25x25 block diagonal: blocks at offsets b*b with dim 2b+1, b=0..4

constexpr int blk_of(int x) { return x == 0 ? 0 : x < 4 ? 1 : x < 9 ? 2 : x < 16 ? 3 : 4; }

template<int E>
__device__ __forceinline__ float pick(const float* D1, const float* D2,
                                      const float* D3, const float* D4) {
    constexpr int r = E / 25, c = E % 25;
    constexpr int b = blk_of(r);
    static_assert(blk_of(c) == b, "pick only on block entries");
    constexpr int off = b * b, d = 2 * b + 1;
    constexpr int li = (r - off) * d + (c - off);
    if constexpr (b == 0) return 1.0f;
    else if constexpr (b == 1) return D1[li];
    else if constexpr (b == 2) return D2[li];
    else if constexpr (b == 3) return D3[li];
    else return D4[li];
}

// scatter the 165 nonzero-structure entries of one row image into LDS
template<int E>
__device__ __forceinline__ void scat_one(float* __restrict__ s,
                                         const float* D1, const float* D2,
                                         const float* D3, const float* D4) {
    if constexpr (blk_of(E / 25) == blk_of(E % 25)) {
        s[E] = pick<E>(D1, D2, D3, D4);
    }
}

template<size_t... I>
__device__ __forceinline__ void scatter_all(float* __restrict__ s,
                                            const float* D1, const float* D2,
                                            const float* D3, const float* D4,
                                            std::index_sequence<I...>) {
    (scat_one<(int)I>(s, D1, D2, D3, D4), ...);
}

// native clang vector type: required by __builtin_nontemporal_store
typedef float v4f __attribute__((ext_vector_type(4)));

// ---------------- kernel ----------------
// Block: 256 threads = 256 points, 8 chunks of 32 points.
// LDS: 32 rows x 625 floats = 80,000 B -> 2 blocks/CU, 8 waves/CU.
// Zero-structure positions written once; nonzero slots overwritten per chunk.
// Copy phase: contiguous 16B-aligned nontemporal v4f stream (chunk byte
// base = 32*2500*k, divisible by 16).

__global__ __launch_bounds__(256, 2)
void wigner_align_z_kernel(const float* __restrict__ xyz, float* __restrict__ out, int Ntot) {
    __shared__ float buf[32 * 625];

    const int t = threadIdx.x;
    const int gp = blockIdx.x * 256 + t;

    float x = 0.0f, y = 0.0f, z = 1.0f;
    if (gp < Ntot) {
        x = xyz[3 * gp + 0];
        y = xyz[3 * gp + 1];
        z = xyz[3 * gp + 2];
    }

    // angles without trig: ct = vz (clipped), st = sqrt(1-ct^2), cp/sp from x,y
    const float r2 = x * x + y * y + z * z;
    const float rinv = rsqrtf(fmaxf(r2, 1e-24f));
    const float ct = fminf(fmaxf(z * rinv, -1.0f), 1.0f);
    const float st = sqrtf(fmaxf(1.0f - ct * ct, 0.0f));
    const float rxy2 = x * x + y * y;
    float cp = 1.0f, sp = 0.0f;
    if (rxy2 > 0.0f) {
        const float ri = rsqrtf(rxy2);
        cp = x * ri;
        sp = y * ri;
    }

    // R1 in real-SH l=1 basis order (y,z,x), row-major 3x3
    float D1[9] = {cp,      0.0f, -sp,
                   st * sp, ct,   st * cp,
                   ct * sp, -st,  ct * cp};

    float D2[25] = {};
    apply_terms<T2>(D2, D1, D1, std::make_index_sequence<(size_t)T2.n>{});
    float D3[49] = {};
    apply_terms<T3>(D3, D1, D2, std::make_index_sequence<(size_t)T3.n>{});
    float D4[81] = {};
    apply_terms<T4>(D4, D1, D3, std::make_index_sequence<(size_t)T4.n>{});

    // zero the structural-zero positions (whole buffer, once)
    v4f* b4 = (v4f*)buf;
    const v4f z4 = {0.0f, 0.0f, 0.0f, 0.0f};
#pragma unroll 4
    for (int k = t; k < 5000; k += 256) b4[k] = z4;
    __syncthreads();

    const long long blk_f = (long long)blockIdx.x * 256 * 625;

    for (int c = 0; c < 8; ++c) {
        const int chunk_base_pt = blockIdx.x * 256 + c * 32;
        if (chunk_base_pt >= Ntot) break;  // uniform across block

        // scatter: the 32 owning threads write their 165 nonzero entries
        if ((t >> 5) == c && gp < Ntot) {
            float* s = &buf[(t & 31) * 625];
            scatter_all(s, D1, D2, D3, D4, std::make_index_sequence<625>{});
        }
        __syncthreads();

        const int vp = min(32, Ntot - chunk_base_pt);
        const long long out_f = blk_f + (long long)c * 32 * 625;
        if (vp == 32) {
            const v4f* src = (const v4f*)buf;
            v4f* dst = (v4f*)(out + out_f);
#pragma unroll 4
            for (int k = t; k < 5000; k += 256) {
                __builtin_nontemporal_store(src[k], dst + k);
            }
        } else {
            const int vf = vp * 625;
            for (int k = t; k < vf; k += 256) {
                out[out_f + k] = buf[k];
            }
        }
        __syncthreads();
    }
}

extern "C" void kernel_launch(void* const* d_in, const int* in_sizes, int n_in,
                              void* d_out, int out_size, void* d_ws, size_t ws_size,
                              hipStream_t stream) {
    const float* xyz = (const float*)d_in[0];
    float* out = (float*)d_out;
    const int N = in_sizes[0] / 3;
    const int blocks = (N + 255) / 256;
    hipLaunchKernelGGL(wigner_align_z_kernel, dim3(blocks), dim3(256), 0, stream,
                       xyz, out, N);
}